// Round 1
// baseline (137.949 us; speedup 1.0000x reference)
//
#include <hip/hip_runtime.h>
#include <hip/hip_bf16.h>
#include <math.h>

#define SEQ 8192
#define DIN 512
#define DH  64
#define SG  16                // sequence splits (R13: 8->16 for 3 blocks/CU occupancy)
#define CHUNK (SEQ / SG)      // 512 K-rows per flash block
#define BK  64                // K/V rows per iteration
#define NIT (CHUNK / BK)      // 8 iterations
#define LDK 64                // flash LDS row stride (bf16): exactly 128B, XOR-swizzled
#define SXP 516               // padded fp32 x row stride (pgemm)

typedef float f32x4 __attribute__((ext_vector_type(4)));
typedef short short8 __attribute__((ext_vector_type(8)));
typedef ushort us4 __attribute__((ext_vector_type(4)));

static __device__ __forceinline__ ushort bf16_of(float v) {
  __hip_bfloat16 h = __float2bfloat16(v);
  return *reinterpret_cast<ushort*>(&h);
}
static __device__ __forceinline__ float f_of_bf16(ushort u) {
  __hip_bfloat16 h;
  *reinterpret_cast<ushort*>(&h) = u;
  return __bfloat162float(h);
}
static __device__ __forceinline__ f32x4 mfma16(short8 a, short8 b, f32x4 c) {
  return __builtin_amdgcn_mfma_f32_16x16x32_bf16(a, b, c, 0, 0, 0);
}
static __device__ __forceinline__ uint pack_bf16(float a, float b) {
  __hip_bfloat162 h2 = __float22bfloat162_rn(make_float2(a, b));
  return *reinterpret_cast<uint*>(&h2);
}
// K-row permutation (R12-proven): physical row p -> LDS slot, chosen so the
// S^T C-layout ownership coincides with the PV B-operand k-ownership,
// making the P^T fragment pure register renaming.
static __device__ __forceinline__ int slot_of(int p) {
  return ((((p >> 2) & 1) * 2 + (p >> 5)) << 4) | (((p >> 3) & 3) << 2) | (p & 3);
}
// R13: XOR chunk swizzle for the 128B-stride flash LDS tiles.  col is a
// 16B-aligned ushort offset; XOR the 16B-chunk index with (row&7).  Write
// and read use the same involution, preserving the 8-phase minimum for
// wave64 ds_read_b128 while removing the +8 pad (55296B -> 49152B LDS,
// 2 -> 3 blocks/CU).
static __device__ __forceinline__ int swz(int row, int col) {
  return col ^ ((row & 7) << 3);
}

// ---------------------------------------------------------------------------
// Kernel 1 (pgemm v4, UNCHANGED): prep folded in.  W read directly in fp32;
// scale (+0.125*log2e for Wq) / transpose / hi-lo split happen in-register
// at fragment-build time.  Register-prefetch ping-pong on the 32 fp32 W
// values per (kt,m) group (R10-proven decoupling recipe).
// ---------------------------------------------------------------------------
__global__ __launch_bounds__(256, 2) void pgemm_kernel(
    const float* __restrict__ x,  const float* __restrict__ Wq,
    const float* __restrict__ Wk, const float* __restrict__ Wv,
    ushort* __restrict__ Qh, ushort* __restrict__ Ql,
    ushort* __restrict__ Kh, ushort* __restrict__ Kl,
    ushort* __restrict__ Vt) {
  __shared__ float sx[16][SXP];               // 33 KB; reused as merge buf
  float* mb = &sx[0][0];

  const int tid = threadIdx.x;
  const int wv = tid >> 6, lane = tid & 63;
  const int ln = lane & 15, qd = lane >> 4;
  const int rb = blockIdx.x * 16;

  {
    const float4* xg = reinterpret_cast<const float4*>(x + (size_t)rb * DIN);
#pragma unroll
    for (int j = 0; j < 8; ++j) {
      const int idx = tid + 256 * j;
      const int row = idx >> 7;
      const int col = (idx & 127) * 4;
      *reinterpret_cast<float4*>(&sx[row][col]) = xg[idx];
    }
  }
  __syncthreads();

  f32x4 acc[3][4];
#pragma unroll
  for (int m = 0; m < 3; ++m)
#pragma unroll
    for (int nt = 0; nt < 4; ++nt)
#pragma unroll
      for (int i = 0; i < 4; ++i) acc[m][nt][i] = 0.f;

  const int kb = wv * 128;
  // per-lane base offset into W[k][n] (row-major 512x64): k = kb+qd*8, n = ln
  const int wbase = (kb + qd * 8) * 64 + ln;

  float wf[2][32];
#define LDW(kt_, m_, buf_)                                                     \
  do {                                                                         \
    const float* W_ = ((m_) == 0) ? Wq : (((m_) == 1) ? Wk : Wv);              \
    const int o_ = wbase + (kt_) * 32 * 64;                                    \
    _Pragma("unroll") for (int nt = 0; nt < 4; ++nt)                           \
      _Pragma("unroll") for (int j = 0; j < 8; ++j)                            \
        wf[buf_][nt * 8 + j] = W_[o_ + j * 64 + nt * 16];                      \
  } while (0)

  LDW(0, 0, 0);
#pragma unroll
  for (int kt = 0; kt < 4; ++kt) {
    const int k0 = kb + kt * 32;
    float xs[8];
    *reinterpret_cast<float4*>(xs) =
        *reinterpret_cast<const float4*>(&sx[ln][k0 + qd * 8]);
    *reinterpret_cast<float4*>(xs + 4) =
        *reinterpret_cast<const float4*>(&sx[ln][k0 + qd * 8 + 4]);
    ushort ah[8] __attribute__((aligned(16)));
    ushort al[8] __attribute__((aligned(16)));
#pragma unroll
    for (int j = 0; j < 8; ++j) {
      const ushort h = bf16_of(xs[j]);
      ah[j] = h;
      al[j] = bf16_of(xs[j] - f_of_bf16(h));
    }
    const short8 Ah = *reinterpret_cast<short8*>(ah);
    const short8 Al = *reinterpret_cast<short8*>(al);
#pragma unroll
    for (int m = 0; m < 3; ++m) {
      const int g = kt * 3 + m;               // compile-time (unrolled)
      const int buf = g & 1;
      if (g < 11) {
        const int gn = g + 1;
        LDW(gn / 3, gn % 3, buf ^ 1);         // prefetch next group's W fp32
      }
      const float scale = (m == 0) ? 0.125f * 1.44269504088896f : 1.0f;
#pragma unroll
      for (int nt = 0; nt < 4; ++nt) {
        ushort bh8[8] __attribute__((aligned(16)));
        ushort bl8[8] __attribute__((aligned(16)));
#pragma unroll
        for (int j = 0; j < 8; ++j) {
          const float v = wf[buf][nt * 8 + j] * scale;
          const ushort h = bf16_of(v);
          bh8[j] = h;
          bl8[j] = bf16_of(v - f_of_bf16(h));
        }
        const short8 bh = *reinterpret_cast<short8*>(bh8);
        const short8 bl = *reinterpret_cast<short8*>(bl8);
        acc[m][nt] = mfma16(Ah, bh, acc[m][nt]);
        acc[m][nt] = mfma16(Ah, bl, acc[m][nt]);
        acc[m][nt] = mfma16(Al, bh, acc[m][nt]);
      }
    }
  }
#undef LDW

  const int eidx = (qd * 4) * 64 + ln;
  __syncthreads();
  if (wv >= 2) {
    float* b = mb + (size_t)(wv - 2) * 3072;
#pragma unroll
    for (int m = 0; m < 3; ++m)
#pragma unroll
      for (int nt = 0; nt < 4; ++nt)
#pragma unroll
        for (int r = 0; r < 4; ++r)
          b[m * 1024 + eidx + r * 64 + nt * 16] = acc[m][nt][r];
  }
  __syncthreads();
  if (wv < 2) {
    const float* b = mb + (size_t)wv * 3072;
#pragma unroll
    for (int m = 0; m < 3; ++m)
#pragma unroll
      for (int nt = 0; nt < 4; ++nt)
#pragma unroll
        for (int r = 0; r < 4; ++r)
          acc[m][nt][r] += b[m * 1024 + eidx + r * 64 + nt * 16];
  }
  __syncthreads();
  if (wv == 1) {
#pragma unroll
    for (int m = 0; m < 3; ++m)
#pragma unroll
      for (int nt = 0; nt < 4; ++nt)
#pragma unroll
        for (int r = 0; r < 4; ++r)
          mb[m * 1024 + eidx + r * 64 + nt * 16] = acc[m][nt][r];
  }
  __syncthreads();
  if (wv == 0) {
#pragma unroll
    for (int m = 0; m < 3; ++m)
#pragma unroll
      for (int nt = 0; nt < 4; ++nt)
#pragma unroll
        for (int r = 0; r < 4; ++r)
          acc[m][nt][r] += mb[m * 1024 + eidx + r * 64 + nt * 16];

#pragma unroll
    for (int m = 0; m < 2; ++m) {
      ushort* H = (m == 0) ? Qh : Kh;
      ushort* L = (m == 0) ? Ql : Kl;
#pragma unroll
      for (int nt = 0; nt < 4; ++nt)
#pragma unroll
        for (int r = 0; r < 4; ++r) {
          const float v = acc[m][nt][r];
          const int row = rb + qd * 4 + r;
          const int col = nt * 16 + ln;
          const ushort h = bf16_of(v);
          H[(size_t)row * DH + col] = h;
          L[(size_t)row * DH + col] = bf16_of(v - f_of_bf16(h));
        }
    }
#pragma unroll
    for (int nt = 0; nt < 4; ++nt) {
      ushort vp[4] __attribute__((aligned(8)));
#pragma unroll
      for (int r = 0; r < 4; ++r) vp[r] = bf16_of(acc[2][nt][r]);
      *reinterpret_cast<us4*>(Vt + (size_t)(nt * 16 + ln) * SEQ + rb + qd * 4) =
          *reinterpret_cast<us4*>(vp);
    }
  }
}

// ---------------------------------------------------------------------------
// Kernel 2 (flash v6 = R12 flash v5 + R13 occupancy): 2 Q-sets/wave +
// permuted K staging (gather-free P^T) + double-buffered LDS (one barrier
// per iter).  R13: LDS 55296->49152 B (LDK=64 + XOR chunk swizzle) so 3
// blocks/CU fit, and SG 8->16 so the grid (1024 blocks) actually populates
// the 3rd slot — 8 -> 12 waves/CU for the latency-bound mixed pipes.
// ---------------------------------------------------------------------------
__global__ __launch_bounds__(256, 3) void flash_kernel(
    const ushort* __restrict__ Qh, const ushort* __restrict__ Ql,
    const ushort* __restrict__ Kh, const ushort* __restrict__ Kl,
    const ushort* __restrict__ Vt,
    ushort* __restrict__ Opart, float* __restrict__ Mpart,
    float* __restrict__ Lpart) {
  __shared__ __attribute__((aligned(16))) ushort sKh[2][BK][LDK];  // 16 KB
  __shared__ __attribute__((aligned(16))) ushort sKl[2][BK][LDK];  // 16 KB
  __shared__ __attribute__((aligned(16))) ushort sVt[2][DH][LDK];  // 16 KB

  const int tid  = threadIdx.x;
  const int wv   = tid >> 6;
  const int lane = tid & 63;
  const int ln   = lane & 15;
  const int qd   = lane >> 4;
  const int bid  = blockIdx.x;
  const int sg   = bid & (SG - 1);
  const int qt   = bid / SG;        // 0..63 (128-row Q tiles)
  const int qrow0  = qt * 128 + wv * 32;   // set s adds s*16
  const int k0base = sg * CHUNK;

  const int r0 = tid >> 3, g0 = (tid & 7) * 8;
  const int r1 = r0 + 32,  g1 = g0;
  const int sr0 = slot_of(r0), sr1 = slot_of(r1);   // permuted K slots

  const ushort one_u = (ln == 0) ? (ushort)0x3F80 : (ushort)0;
  short8 afr1;
#pragma unroll
  for (int j = 0; j < 8; ++j) afr1[j] = (short)one_u;

  short8 bqh[2][2], bql[2][2];
#pragma unroll
  for (int s = 0; s < 2; ++s)
#pragma unroll
    for (int kt = 0; kt < 2; ++kt) {
      bqh[s][kt] = *reinterpret_cast<const short8*>(
          Qh + (size_t)(qrow0 + s * 16 + ln) * DH + kt * 32 + qd * 8);
      bql[s][kt] = *reinterpret_cast<const short8*>(
          Ql + (size_t)(qrow0 + s * 16 + ln) * DH + kt * 32 + qd * 8);
    }

  f32x4 accO[2][4], accL[2];
  float m_run[2] = {-INFINITY, -INFINITY};
#pragma unroll
  for (int s = 0; s < 2; ++s) {
#pragma unroll
    for (int nt = 0; nt < 4; ++nt)
#pragma unroll
      for (int i = 0; i < 4; ++i) accO[s][nt][i] = 0.f;
#pragma unroll
    for (int i = 0; i < 4; ++i) accL[s][i] = 0.f;
  }

  uint4 pk0, pk1, pl0, pl1, pv0, pv1;
#define LOAD_TILES(k0_)                                                        \
  do {                                                                         \
    pk0 = *reinterpret_cast<const uint4*>(Kh + (size_t)((k0_) + r0) * DH + g0);\
    pk1 = *reinterpret_cast<const uint4*>(Kh + (size_t)((k0_) + r1) * DH + g1);\
    pl0 = *reinterpret_cast<const uint4*>(Kl + (size_t)((k0_) + r0) * DH + g0);\
    pl1 = *reinterpret_cast<const uint4*>(Kl + (size_t)((k0_) + r1) * DH + g1);\
    pv0 = *reinterpret_cast<const uint4*>(Vt + (size_t)r0 * SEQ + (k0_) + g0); \
    pv1 = *reinterpret_cast<const uint4*>(Vt + (size_t)r1 * SEQ + (k0_) + g1); \
  } while (0)
#define STORE_TILES(b_)                                                        \
  do {                                                                         \
    *reinterpret_cast<uint4*>(&sKh[b_][sr0][swz(sr0, g0)]) = pk0;              \
    *reinterpret_cast<uint4*>(&sKh[b_][sr1][swz(sr1, g1)]) = pk1;              \
    *reinterpret_cast<uint4*>(&sKl[b_][sr0][swz(sr0, g0)]) = pl0;              \
    *reinterpret_cast<uint4*>(&sKl[b_][sr1][swz(sr1, g1)]) = pl1;              \
    *reinterpret_cast<uint4*>(&sVt[b_][r0][swz(r0, g0)])   = pv0;              \
    *reinterpret_cast<uint4*>(&sVt[b_][r1][swz(r1, g1)])   = pv1;              \
  } while (0)

  LOAD_TILES(k0base);
  STORE_TILES(0);
  __syncthreads();

  for (int it = 0; it < NIT; ++it) {
    const int cur = it & 1;
    const int k0n = k0base + ((it + 1 < NIT) ? (it + 1) : it) * BK;
    LOAD_TILES(k0n);          // global loads for next iter, hidden by compute

    f32x4 accS[2][4];
#pragma unroll
    for (int nt = 0; nt < 4; ++nt) {
#pragma unroll
      for (int s = 0; s < 2; ++s)
#pragma unroll
        for (int i = 0; i < 4; ++i) accS[s][nt][i] = 0.f;
      const int kr = nt * 16 + ln;
      const short8 kh0 = *reinterpret_cast<const short8*>(&sKh[cur][kr][swz(kr, qd * 8)]);
      const short8 kh1 = *reinterpret_cast<const short8*>(&sKh[cur][kr][swz(kr, 32 + qd * 8)]);
      const short8 kl0 = *reinterpret_cast<const short8*>(&sKl[cur][kr][swz(kr, qd * 8)]);
      const short8 kl1 = *reinterpret_cast<const short8*>(&sKl[cur][kr][swz(kr, 32 + qd * 8)]);
#pragma unroll
      for (int s = 0; s < 2; ++s) {
        accS[s][nt] = mfma16(kh0, bqh[s][0], accS[s][nt]);
        accS[s][nt] = mfma16(kh1, bqh[s][1], accS[s][nt]);
        accS[s][nt] = mfma16(kh0, bql[s][0], accS[s][nt]);
        accS[s][nt] = mfma16(kh1, bql[s][1], accS[s][nt]);
        accS[s][nt] = mfma16(kl0, bqh[s][0], accS[s][nt]);
        accS[s][nt] = mfma16(kl1, bqh[s][1], accS[s][nt]);
      }
    }

    uint pkd[2][4][2];
#pragma unroll
    for (int s = 0; s < 2; ++s) {
      float tmax = fmaxf(
          fmaxf(fmaxf(accS[s][0][0], accS[s][0][1]), fmaxf(accS[s][0][2], accS[s][0][3])),
          fmaxf(fmaxf(accS[s][1][0], accS[s][1][1]), fmaxf(accS[s][1][2], accS[s][1][3])));
      tmax = fmaxf(tmax, fmaxf(
          fmaxf(fmaxf(accS[s][2][0], accS[s][2][1]), fmaxf(accS[s][2][2], accS[s][2][3])),
          fmaxf(fmaxf(accS[s][3][0], accS[s][3][1]), fmaxf(accS[s][3][2], accS[s][3][3]))));
      tmax = fmaxf(tmax, __shfl_xor(tmax, 16));
      tmax = fmaxf(tmax, __shfl_xor(tmax, 32));
      const float mnew  = fmaxf(m_run[s], tmax);
      const float alpha = exp2f(m_run[s] - mnew);
      m_run[s] = mnew;
#pragma unroll
      for (int nt = 0; nt < 4; ++nt) {
        const float p0 = exp2f(accS[s][nt][0] - mnew);
        const float p1 = exp2f(accS[s][nt][1] - mnew);
        const float p2 = exp2f(accS[s][nt][2] - mnew);
        const float p3 = exp2f(accS[s][nt][3] - mnew);
        pkd[s][nt][0] = pack_bf16(p0, p1);
        pkd[s][nt][1] = pack_bf16(p2, p3);
#pragma unroll
        for (int i = 0; i < 4; ++i) accO[s][nt][i] *= alpha;
      }
      accL[s][0] *= alpha;
    }

    // O^T += V^T · P^T ; l += 1~ · P^T — P^T frag is pure register renaming
#pragma unroll
    for (int kt2 = 0; kt2 < 2; ++kt2) {
      short8 pfrag[2];
#pragma unroll
      for (int s = 0; s < 2; ++s) {
        uint4 du;
        du.x = pkd[s][kt2][0];
        du.y = pkd[s][kt2][1];
        du.z = pkd[s][kt2 + 2][0];
        du.w = pkd[s][kt2 + 2][1];
        pfrag[s] = *reinterpret_cast<short8*>(&du);
      }
#pragma unroll
      for (int nt2 = 0; nt2 < 4; ++nt2) {
        const int vr = nt2 * 16 + ln;
        const short8 vA = *reinterpret_cast<const short8*>(
            &sVt[cur][vr][swz(vr, kt2 * 32 + qd * 8)]);
        accO[0][nt2] = mfma16(vA, pfrag[0], accO[0][nt2]);
        accO[1][nt2] = mfma16(vA, pfrag[1], accO[1][nt2]);
      }
      accL[0] = mfma16(afr1, pfrag[0], accL[0]);
      accL[1] = mfma16(afr1, pfrag[1], accL[1]);
    }

    if (it + 1 < NIT) {
      STORE_TILES(cur ^ 1);
      __syncthreads();
    }
  }
#undef LOAD_TILES
#undef STORE_TILES

#pragma unroll
  for (int s = 0; s < 2; ++s) {
    const int qrow = qrow0 + s * 16 + ln;
    ushort* Ob = Opart + ((size_t)sg * SEQ + qrow) * DH;
#pragma unroll
    for (int nt = 0; nt < 4; ++nt) {
      ushort op[4] __attribute__((aligned(8)));
#pragma unroll
      for (int r = 0; r < 4; ++r) op[r] = bf16_of(accO[s][nt][r]);
      *reinterpret_cast<us4*>(Ob + nt * 16 + qd * 4) =
          *reinterpret_cast<us4*>(op);
    }
    if (qd == 0) {
      Mpart[(size_t)sg * SEQ + qrow] = m_run[s];
      Lpart[(size_t)sg * SEQ + qrow] = accL[s][0];
    }
  }
}

// ---------------------------------------------------------------------------
// Kernel 3: merge of the SG=16 seq-split partials (exp2 domain), vec x4.
// ---------------------------------------------------------------------------
__global__ __launch_bounds__(256) void merge_kernel(
    const ushort* __restrict__ Opart, const float* __restrict__ Mpart,
    const float* __restrict__ Lpart, float* __restrict__ out) {
  const int idx = blockIdx.x * 256 + threadIdx.x;   // 0 .. SEQ*16
  const int row = idx >> 4;
  const int c4  = (idx & 15) * 4;

  float m[SG];
  float M = -INFINITY;
#pragma unroll
  for (int i = 0; i < SG; ++i) {
    m[i] = Mpart[(size_t)i * SEQ + row];
    M = fmaxf(M, m[i]);
  }
  float L = 0.f;
  float a0 = 0.f, a1 = 0.f, a2 = 0.f, a3 = 0.f;
#pragma unroll
  for (int i = 0; i < SG; ++i) {
    const float w = exp2f(m[i] - M);
    L += w * Lpart[(size_t)i * SEQ + row];
    const us4 o = *reinterpret_cast<const us4*>(
        Opart + ((size_t)i * SEQ + row) * DH + c4);
    a0 += w * f_of_bf16(o[0]);
    a1 += w * f_of_bf16(o[1]);
    a2 += w * f_of_bf16(o[2]);
    a3 += w * f_of_bf16(o[3]);
  }
  const float rL = 1.0f / L;
  float4 res = make_float4(a0 * rL, a1 * rL, a2 * rL, a3 * rL);
  *reinterpret_cast<float4*>(out + (size_t)row * DH + c4) = res;
}

// ---------------------------------------------------------------------------
extern "C" void kernel_launch(void* const* d_in, const int* in_sizes, int n_in,
                              void* d_out, int out_size, void* d_ws, size_t ws_size,
                              hipStream_t stream) {
  const float* x  = (const float*)d_in[0];
  const float* Wq = (const float*)d_in[1];
  const float* Wk = (const float*)d_in[2];
  const float* Wv = (const float*)d_in[3];
  float* out = (float*)d_out;

  // workspace layout — 23,068,672 B (R13: SG=16 partials).
  const size_t S64 = (size_t)SEQ * DH;        // 524288
  ushort* Qh = (ushort*)d_ws;
  ushort* Ql = Qh + S64;
  ushort* Kh = Ql + S64;
  ushort* Kl = Kh + S64;
  ushort* Vt = Kl + S64;
  ushort* Op = Vt + S64;                      // [SG][SEQ][DH] bf16
  float*  Mp = (float*)(Op + (size_t)SG * S64);
  float*  Lp = Mp + (size_t)SG * SEQ;

  pgemm_kernel<<<SEQ / 16, 256, 0, stream>>>(x, Wq, Wk, Wv, Qh, Ql, Kh, Kl, Vt);
  flash_kernel<<<(SEQ / 128) * SG, 256, 0, stream>>>(Qh, Ql, Kh, Kl, Vt, Op, Mp, Lp);
  merge_kernel<<<(SEQ * 16) / 256, 256, 0, stream>>>(Op, Mp, Lp, out);
}

// Round 2
// 132.802 us; speedup vs baseline: 1.0388x; 1.0388x over previous
//
#include <hip/hip_runtime.h>
#include <hip/hip_bf16.h>
#include <math.h>

#define SEQ 8192
#define DIN 512
#define DH  64
#define SG  12                // R14: 12 seq-chunks -> grid 64*12=768 = 3 blocks/CU
                              // exactly (tail-free), chunks of 11/10 BK-tiles
#define BK  64                // K/V rows per iteration
#define NT_TOT (SEQ / BK)     // 128 BK-tiles total
#define LDK 64                // flash LDS row stride (bf16): 128B, XOR-swizzled
#define SXP 516               // padded fp32 x row stride (pgemm)

typedef float f32x4 __attribute__((ext_vector_type(4)));
typedef short short8 __attribute__((ext_vector_type(8)));
typedef ushort us4 __attribute__((ext_vector_type(4)));

static __device__ __forceinline__ ushort bf16_of(float v) {
  __hip_bfloat16 h = __float2bfloat16(v);
  return *reinterpret_cast<ushort*>(&h);
}
static __device__ __forceinline__ float f_of_bf16(ushort u) {
  __hip_bfloat16 h;
  *reinterpret_cast<ushort*>(&h) = u;
  return __bfloat162float(h);
}
static __device__ __forceinline__ f32x4 mfma16(short8 a, short8 b, f32x4 c) {
  return __builtin_amdgcn_mfma_f32_16x16x32_bf16(a, b, c, 0, 0, 0);
}
static __device__ __forceinline__ uint pack_bf16(float a, float b) {
  __hip_bfloat162 h2 = __float22bfloat162_rn(make_float2(a, b));
  return *reinterpret_cast<uint*>(&h2);
}
// K-row permutation (R12-proven): physical row p -> LDS slot, chosen so the
// S^T C-layout ownership coincides with the PV B-operand k-ownership,
// making the P^T fragment pure register renaming.
static __device__ __forceinline__ int slot_of(int p) {
  return ((((p >> 2) & 1) * 2 + (p >> 5)) << 4) | (((p >> 3) & 3) << 2) | (p & 3);
}
// R13-proven XOR chunk swizzle (measured: bank conflicts 3.1M -> 0): col is
// a 16B-aligned ushort offset; XOR the 16B-chunk index with (row&7).  Same
// involution on write and read; LDS stride exactly 128B (LDK=64).
static __device__ __forceinline__ int swz(int row, int col) {
  return col ^ ((row & 7) << 3);
}

// ---------------------------------------------------------------------------
// Kernel 1 (pgemm v4, UNCHANGED): prep folded in.  W read directly in fp32;
// scale (+0.125*log2e for Wq) / transpose / hi-lo split happen in-register
// at fragment-build time.  Register-prefetch ping-pong on the 32 fp32 W
// values per (kt,m) group (R10-proven decoupling recipe).
// ---------------------------------------------------------------------------
__global__ __launch_bounds__(256, 2) void pgemm_kernel(
    const float* __restrict__ x,  const float* __restrict__ Wq,
    const float* __restrict__ Wk, const float* __restrict__ Wv,
    ushort* __restrict__ Qh, ushort* __restrict__ Ql,
    ushort* __restrict__ Kh, ushort* __restrict__ Kl,
    ushort* __restrict__ Vt) {
  __shared__ float sx[16][SXP];               // 33 KB; reused as merge buf
  float* mb = &sx[0][0];

  const int tid = threadIdx.x;
  const int wv = tid >> 6, lane = tid & 63;
  const int ln = lane & 15, qd = lane >> 4;
  const int rb = blockIdx.x * 16;

  {
    const float4* xg = reinterpret_cast<const float4*>(x + (size_t)rb * DIN);
#pragma unroll
    for (int j = 0; j < 8; ++j) {
      const int idx = tid + 256 * j;
      const int row = idx >> 7;
      const int col = (idx & 127) * 4;
      *reinterpret_cast<float4*>(&sx[row][col]) = xg[idx];
    }
  }
  __syncthreads();

  f32x4 acc[3][4];
#pragma unroll
  for (int m = 0; m < 3; ++m)
#pragma unroll
    for (int nt = 0; nt < 4; ++nt)
#pragma unroll
      for (int i = 0; i < 4; ++i) acc[m][nt][i] = 0.f;

  const int kb = wv * 128;
  // per-lane base offset into W[k][n] (row-major 512x64): k = kb+qd*8, n = ln
  const int wbase = (kb + qd * 8) * 64 + ln;

  float wf[2][32];
#define LDW(kt_, m_, buf_)                                                     \
  do {                                                                         \
    const float* W_ = ((m_) == 0) ? Wq : (((m_) == 1) ? Wk : Wv);              \
    const int o_ = wbase + (kt_) * 32 * 64;                                    \
    _Pragma("unroll") for (int nt = 0; nt < 4; ++nt)                           \
      _Pragma("unroll") for (int j = 0; j < 8; ++j)                            \
        wf[buf_][nt * 8 + j] = W_[o_ + j * 64 + nt * 16];                      \
  } while (0)

  LDW(0, 0, 0);
#pragma unroll
  for (int kt = 0; kt < 4; ++kt) {
    const int k0 = kb + kt * 32;
    float xs[8];
    *reinterpret_cast<float4*>(xs) =
        *reinterpret_cast<const float4*>(&sx[ln][k0 + qd * 8]);
    *reinterpret_cast<float4*>(xs + 4) =
        *reinterpret_cast<const float4*>(&sx[ln][k0 + qd * 8 + 4]);
    ushort ah[8] __attribute__((aligned(16)));
    ushort al[8] __attribute__((aligned(16)));
#pragma unroll
    for (int j = 0; j < 8; ++j) {
      const ushort h = bf16_of(xs[j]);
      ah[j] = h;
      al[j] = bf16_of(xs[j] - f_of_bf16(h));
    }
    const short8 Ah = *reinterpret_cast<short8*>(ah);
    const short8 Al = *reinterpret_cast<short8*>(al);
#pragma unroll
    for (int m = 0; m < 3; ++m) {
      const int g = kt * 3 + m;               // compile-time (unrolled)
      const int buf = g & 1;
      if (g < 11) {
        const int gn = g + 1;
        LDW(gn / 3, gn % 3, buf ^ 1);         // prefetch next group's W fp32
      }
      const float scale = (m == 0) ? 0.125f * 1.44269504088896f : 1.0f;
#pragma unroll
      for (int nt = 0; nt < 4; ++nt) {
        ushort bh8[8] __attribute__((aligned(16)));
        ushort bl8[8] __attribute__((aligned(16)));
#pragma unroll
        for (int j = 0; j < 8; ++j) {
          const float v = wf[buf][nt * 8 + j] * scale;
          const ushort h = bf16_of(v);
          bh8[j] = h;
          bl8[j] = bf16_of(v - f_of_bf16(h));
        }
        const short8 bh = *reinterpret_cast<short8*>(bh8);
        const short8 bl = *reinterpret_cast<short8*>(bl8);
        acc[m][nt] = mfma16(Ah, bh, acc[m][nt]);
        acc[m][nt] = mfma16(Ah, bl, acc[m][nt]);
        acc[m][nt] = mfma16(Al, bh, acc[m][nt]);
      }
    }
  }
#undef LDW

  const int eidx = (qd * 4) * 64 + ln;
  __syncthreads();
  if (wv >= 2) {
    float* b = mb + (size_t)(wv - 2) * 3072;
#pragma unroll
    for (int m = 0; m < 3; ++m)
#pragma unroll
      for (int nt = 0; nt < 4; ++nt)
#pragma unroll
        for (int r = 0; r < 4; ++r)
          b[m * 1024 + eidx + r * 64 + nt * 16] = acc[m][nt][r];
  }
  __syncthreads();
  if (wv < 2) {
    const float* b = mb + (size_t)wv * 3072;
#pragma unroll
    for (int m = 0; m < 3; ++m)
#pragma unroll
      for (int nt = 0; nt < 4; ++nt)
#pragma unroll
        for (int r = 0; r < 4; ++r)
          acc[m][nt][r] += b[m * 1024 + eidx + r * 64 + nt * 16];
  }
  __syncthreads();
  if (wv == 1) {
#pragma unroll
    for (int m = 0; m < 3; ++m)
#pragma unroll
      for (int nt = 0; nt < 4; ++nt)
#pragma unroll
        for (int r = 0; r < 4; ++r)
          mb[m * 1024 + eidx + r * 64 + nt * 16] = acc[m][nt][r];
  }
  __syncthreads();
  if (wv == 0) {
#pragma unroll
    for (int m = 0; m < 3; ++m)
#pragma unroll
      for (int nt = 0; nt < 4; ++nt)
#pragma unroll
        for (int r = 0; r < 4; ++r)
          acc[m][nt][r] += mb[m * 1024 + eidx + r * 64 + nt * 16];

#pragma unroll
    for (int m = 0; m < 2; ++m) {
      ushort* H = (m == 0) ? Qh : Kh;
      ushort* L = (m == 0) ? Ql : Kl;
#pragma unroll
      for (int nt = 0; nt < 4; ++nt)
#pragma unroll
        for (int r = 0; r < 4; ++r) {
          const float v = acc[m][nt][r];
          const int row = rb + qd * 4 + r;
          const int col = nt * 16 + ln;
          const ushort h = bf16_of(v);
          H[(size_t)row * DH + col] = h;
          L[(size_t)row * DH + col] = bf16_of(v - f_of_bf16(h));
        }
    }
#pragma unroll
    for (int nt = 0; nt < 4; ++nt) {
      ushort vp[4] __attribute__((aligned(8)));
#pragma unroll
      for (int r = 0; r < 4; ++r) vp[r] = bf16_of(acc[2][nt][r]);
      *reinterpret_cast<us4*>(Vt + (size_t)(nt * 16 + ln) * SEQ + rb + qd * 4) =
          *reinterpret_cast<us4*>(vp);
    }
  }
}

// ---------------------------------------------------------------------------
// Kernel 2 (flash v7): 2 Q-sets/wave + permuted K staging (gather-free P^T)
// + double-buffered LDS (one barrier/iter) + R13 XOR swizzle (0 conflicts,
// 48KB LDS).  R14: grid = 64 qt x 12 sg = 768 = exactly 3 blocks/CU -- all
// blocks resident at t=0, no 4-rounds-in-3-slots tail (R13 post-mortem).
// Chunks are 11 or 10 BK-tiles (8*11 + 4*10 = 128).  Micro: persistent zero
// reg as first-MFMA C (kills 32 v_mov/iter), v_max3-friendly row-max tree.
// ---------------------------------------------------------------------------
__global__ __launch_bounds__(256, 3) void flash_kernel(
    const ushort* __restrict__ Qh, const ushort* __restrict__ Ql,
    const ushort* __restrict__ Kh, const ushort* __restrict__ Kl,
    const ushort* __restrict__ Vt,
    ushort* __restrict__ Opart, float* __restrict__ Mpart,
    float* __restrict__ Lpart) {
  __shared__ __attribute__((aligned(16))) ushort sKh[2][BK][LDK];  // 16 KB
  __shared__ __attribute__((aligned(16))) ushort sKl[2][BK][LDK];  // 16 KB
  __shared__ __attribute__((aligned(16))) ushort sVt[2][DH][LDK];  // 16 KB

  const int tid  = threadIdx.x;
  const int wv   = tid >> 6;
  const int lane = tid & 63;
  const int ln   = lane & 15;
  const int qd   = lane >> 4;
  const int bid  = blockIdx.x;
  const int qt   = bid / SG;            // 0..63 (128-row Q tiles)
  const int sg   = bid - qt * SG;       // 0..11
  // variable-length chunk: first 8 chunks 11 BK-tiles, last 4 chunks 10.
  const int nit    = (sg < 8) ? 11 : 10;
  const int t0     = (sg < 8) ? sg * 11 : 88 + (sg - 8) * 10;
  const int k0base = t0 * BK;
  const int qrow0  = qt * 128 + wv * 32;   // set s adds s*16

  const int r0 = tid >> 3, g0 = (tid & 7) * 8;
  const int r1 = r0 + 32,  g1 = g0;
  const int sr0 = slot_of(r0), sr1 = slot_of(r1);   // permuted K slots

  const ushort one_u = (ln == 0) ? (ushort)0x3F80 : (ushort)0;
  short8 afr1;
#pragma unroll
  for (int j = 0; j < 8; ++j) afr1[j] = (short)one_u;

  short8 bqh[2][2], bql[2][2];
#pragma unroll
  for (int s = 0; s < 2; ++s)
#pragma unroll
    for (int kt = 0; kt < 2; ++kt) {
      bqh[s][kt] = *reinterpret_cast<const short8*>(
          Qh + (size_t)(qrow0 + s * 16 + ln) * DH + kt * 32 + qd * 8);
      bql[s][kt] = *reinterpret_cast<const short8*>(
          Ql + (size_t)(qrow0 + s * 16 + ln) * DH + kt * 32 + qd * 8);
    }

  f32x4 accO[2][4], accL[2];
  float m_run[2] = {-INFINITY, -INFINITY};
#pragma unroll
  for (int s = 0; s < 2; ++s) {
#pragma unroll
    for (int nt = 0; nt < 4; ++nt)
#pragma unroll
      for (int i = 0; i < 4; ++i) accO[s][nt][i] = 0.f;
#pragma unroll
    for (int i = 0; i < 4; ++i) accL[s][i] = 0.f;
  }
  const f32x4 z4 = {0.f, 0.f, 0.f, 0.f};   // persistent zero C-operand

  uint4 pk0, pk1, pl0, pl1, pv0, pv1;
#define LOAD_TILES(k0_)                                                        \
  do {                                                                         \
    pk0 = *reinterpret_cast<const uint4*>(Kh + (size_t)((k0_) + r0) * DH + g0);\
    pk1 = *reinterpret_cast<const uint4*>(Kh + (size_t)((k0_) + r1) * DH + g1);\
    pl0 = *reinterpret_cast<const uint4*>(Kl + (size_t)((k0_) + r0) * DH + g0);\
    pl1 = *reinterpret_cast<const uint4*>(Kl + (size_t)((k0_) + r1) * DH + g1);\
    pv0 = *reinterpret_cast<const uint4*>(Vt + (size_t)r0 * SEQ + (k0_) + g0); \
    pv1 = *reinterpret_cast<const uint4*>(Vt + (size_t)r1 * SEQ + (k0_) + g1); \
  } while (0)
#define STORE_TILES(b_)                                                        \
  do {                                                                         \
    *reinterpret_cast<uint4*>(&sKh[b_][sr0][swz(sr0, g0)]) = pk0;              \
    *reinterpret_cast<uint4*>(&sKh[b_][sr1][swz(sr1, g1)]) = pk1;              \
    *reinterpret_cast<uint4*>(&sKl[b_][sr0][swz(sr0, g0)]) = pl0;              \
    *reinterpret_cast<uint4*>(&sKl[b_][sr1][swz(sr1, g1)]) = pl1;              \
    *reinterpret_cast<uint4*>(&sVt[b_][r0][swz(r0, g0)])   = pv0;              \
    *reinterpret_cast<uint4*>(&sVt[b_][r1][swz(r1, g1)])   = pv1;              \
  } while (0)

  LOAD_TILES(k0base);
  STORE_TILES(0);
  __syncthreads();

  for (int it = 0; it < nit; ++it) {
    const int cur = it & 1;
    const int k0n = k0base + ((it + 1 < nit) ? (it + 1) : it) * BK;
    LOAD_TILES(k0n);          // global loads for next iter, hidden by compute

    f32x4 accS[2][4];
#pragma unroll
    for (int nt = 0; nt < 4; ++nt) {
      const int kr = nt * 16 + ln;
      const short8 kh0 = *reinterpret_cast<const short8*>(&sKh[cur][kr][swz(kr, qd * 8)]);
      const short8 kh1 = *reinterpret_cast<const short8*>(&sKh[cur][kr][swz(kr, 32 + qd * 8)]);
      const short8 kl0 = *reinterpret_cast<const short8*>(&sKl[cur][kr][swz(kr, qd * 8)]);
      const short8 kl1 = *reinterpret_cast<const short8*>(&sKl[cur][kr][swz(kr, 32 + qd * 8)]);
#pragma unroll
      for (int s = 0; s < 2; ++s) {
        accS[s][nt] = mfma16(kh0, bqh[s][0], z4);
        accS[s][nt] = mfma16(kh1, bqh[s][1], accS[s][nt]);
        accS[s][nt] = mfma16(kh0, bql[s][0], accS[s][nt]);
        accS[s][nt] = mfma16(kh1, bql[s][1], accS[s][nt]);
        accS[s][nt] = mfma16(kl0, bqh[s][0], accS[s][nt]);
        accS[s][nt] = mfma16(kl1, bqh[s][1], accS[s][nt]);
      }
    }

    uint pkd[2][4][2];
#pragma unroll
    for (int s = 0; s < 2; ++s) {
      // left-leaning triples -> clang fuses v_max3_f32 (8 ops vs 15)
      float tmax = fmaxf(fmaxf(accS[s][0][0], accS[s][0][1]), accS[s][0][2]);
      tmax = fmaxf(fmaxf(tmax, accS[s][0][3]), accS[s][1][0]);
      tmax = fmaxf(fmaxf(tmax, accS[s][1][1]), accS[s][1][2]);
      tmax = fmaxf(fmaxf(tmax, accS[s][1][3]), accS[s][2][0]);
      tmax = fmaxf(fmaxf(tmax, accS[s][2][1]), accS[s][2][2]);
      tmax = fmaxf(fmaxf(tmax, accS[s][2][3]), accS[s][3][0]);
      tmax = fmaxf(fmaxf(tmax, accS[s][3][1]), accS[s][3][2]);
      tmax = fmaxf(tmax, accS[s][3][3]);
      tmax = fmaxf(tmax, __shfl_xor(tmax, 16));
      tmax = fmaxf(tmax, __shfl_xor(tmax, 32));
      const float mnew  = fmaxf(m_run[s], tmax);
      const float alpha = exp2f(m_run[s] - mnew);
      m_run[s] = mnew;
#pragma unroll
      for (int nt = 0; nt < 4; ++nt) {
        const float p0 = exp2f(accS[s][nt][0] - mnew);
        const float p1 = exp2f(accS[s][nt][1] - mnew);
        const float p2 = exp2f(accS[s][nt][2] - mnew);
        const float p3 = exp2f(accS[s][nt][3] - mnew);
        pkd[s][nt][0] = pack_bf16(p0, p1);
        pkd[s][nt][1] = pack_bf16(p2, p3);
#pragma unroll
        for (int i = 0; i < 4; ++i) accO[s][nt][i] *= alpha;
      }
      accL[s][0] *= alpha;
    }

    // O^T += V^T · P^T ; l += 1~ · P^T — P^T frag is pure register renaming
#pragma unroll
    for (int kt2 = 0; kt2 < 2; ++kt2) {
      short8 pfrag[2];
#pragma unroll
      for (int s = 0; s < 2; ++s) {
        uint4 du;
        du.x = pkd[s][kt2][0];
        du.y = pkd[s][kt2][1];
        du.z = pkd[s][kt2 + 2][0];
        du.w = pkd[s][kt2 + 2][1];
        pfrag[s] = *reinterpret_cast<short8*>(&du);
      }
#pragma unroll
      for (int nt2 = 0; nt2 < 4; ++nt2) {
        const int vr = nt2 * 16 + ln;
        const short8 vA = *reinterpret_cast<const short8*>(
            &sVt[cur][vr][swz(vr, kt2 * 32 + qd * 8)]);
        accO[0][nt2] = mfma16(vA, pfrag[0], accO[0][nt2]);
        accO[1][nt2] = mfma16(vA, pfrag[1], accO[1][nt2]);
      }
      accL[0] = mfma16(afr1, pfrag[0], accL[0]);
      accL[1] = mfma16(afr1, pfrag[1], accL[1]);
    }

    if (it + 1 < nit) {
      STORE_TILES(cur ^ 1);
      __syncthreads();
    }
  }
#undef LOAD_TILES
#undef STORE_TILES

#pragma unroll
  for (int s = 0; s < 2; ++s) {
    const int qrow = qrow0 + s * 16 + ln;
    ushort* Ob = Opart + ((size_t)sg * SEQ + qrow) * DH;
#pragma unroll
    for (int nt = 0; nt < 4; ++nt) {
      ushort op[4] __attribute__((aligned(8)));
#pragma unroll
      for (int r = 0; r < 4; ++r) op[r] = bf16_of(accO[s][nt][r]);
      *reinterpret_cast<us4*>(Ob + nt * 16 + qd * 4) =
          *reinterpret_cast<us4*>(op);
    }
    if (qd == 0) {
      Mpart[(size_t)sg * SEQ + qrow] = m_run[s];
      Lpart[(size_t)sg * SEQ + qrow] = accL[s][0];
    }
  }
}

// ---------------------------------------------------------------------------
// Kernel 3: merge of the SG=12 seq-split partials (exp2 domain), vec x4.
// ---------------------------------------------------------------------------
__global__ __launch_bounds__(256) void merge_kernel(
    const ushort* __restrict__ Opart, const float* __restrict__ Mpart,
    const float* __restrict__ Lpart, float* __restrict__ out) {
  const int idx = blockIdx.x * 256 + threadIdx.x;   // 0 .. SEQ*16
  const int row = idx >> 4;
  const int c4  = (idx & 15) * 4;

  float m[SG];
  float M = -INFINITY;
#pragma unroll
  for (int i = 0; i < SG; ++i) {
    m[i] = Mpart[(size_t)i * SEQ + row];
    M = fmaxf(M, m[i]);
  }
  float L = 0.f;
  float a0 = 0.f, a1 = 0.f, a2 = 0.f, a3 = 0.f;
#pragma unroll
  for (int i = 0; i < SG; ++i) {
    const float w = exp2f(m[i] - M);
    L += w * Lpart[(size_t)i * SEQ + row];
    const us4 o = *reinterpret_cast<const us4*>(
        Opart + ((size_t)i * SEQ + row) * DH + c4);
    a0 += w * f_of_bf16(o[0]);
    a1 += w * f_of_bf16(o[1]);
    a2 += w * f_of_bf16(o[2]);
    a3 += w * f_of_bf16(o[3]);
  }
  const float rL = 1.0f / L;
  float4 res = make_float4(a0 * rL, a1 * rL, a2 * rL, a3 * rL);
  *reinterpret_cast<float4*>(out + (size_t)row * DH + c4) = res;
}

// ---------------------------------------------------------------------------
extern "C" void kernel_launch(void* const* d_in, const int* in_sizes, int n_in,
                              void* d_out, int out_size, void* d_ws, size_t ws_size,
                              hipStream_t stream) {
  const float* x  = (const float*)d_in[0];
  const float* Wq = (const float*)d_in[1];
  const float* Wk = (const float*)d_in[2];
  const float* Wv = (const float*)d_in[3];
  float* out = (float*)d_out;

  // workspace layout — ~18.7 MB (R14: SG=12 partials; fits prior 23 MB ws).
  const size_t S64 = (size_t)SEQ * DH;        // 524288
  ushort* Qh = (ushort*)d_ws;
  ushort* Ql = Qh + S64;
  ushort* Kh = Ql + S64;
  ushort* Kl = Kh + S64;
  ushort* Vt = Kl + S64;
  ushort* Op = Vt + S64;                      // [SG][SEQ][DH] bf16
  float*  Mp = (float*)(Op + (size_t)SG * S64);
  float*  Lp = Mp + (size_t)SG * SEQ;

  pgemm_kernel<<<SEQ / 16, 256, 0, stream>>>(x, Wq, Wk, Wv, Qh, Ql, Kh, Kl, Vt);
  flash_kernel<<<(SEQ / 128) * SG, 256, 0, stream>>>(Qh, Ql, Kh, Kl, Vt, Op, Mp, Lp);
  merge_kernel<<<(SEQ * 16) / 256, 256, 0, stream>>>(Op, Mp, Lp, out);
}

// Round 3
// 129.656 us; speedup vs baseline: 1.0640x; 1.0243x over previous
//
#include <hip/hip_runtime.h>
#include <hip/hip_bf16.h>
#include <math.h>

#define SEQ 8192
#define DIN 512
#define DH  64
#define SG  8                 // R15: back to 8 (grid 512 = 2 blocks/CU exact;
                              // triple-buffered LDS caps at 2/CU anyway)
#define CHUNK (SEQ / SG)      // 1024 K-rows per flash block
#define BK  64                // K/V rows per iteration
#define NIT (CHUNK / BK)      // 16 iterations (compile-time)
#define LDK 64                // flash LDS row stride (bf16): 128B, XOR-swizzled
#define SXP 516               // padded fp32 x row stride (pgemm)

typedef float f32x4 __attribute__((ext_vector_type(4)));
typedef short short8 __attribute__((ext_vector_type(8)));
typedef ushort us4 __attribute__((ext_vector_type(4)));

static __device__ __forceinline__ ushort bf16_of(float v) {
  __hip_bfloat16 h = __float2bfloat16(v);
  return *reinterpret_cast<ushort*>(&h);
}
static __device__ __forceinline__ float f_of_bf16(ushort u) {
  __hip_bfloat16 h;
  *reinterpret_cast<ushort*>(&h) = u;
  return __bfloat162float(h);
}
static __device__ __forceinline__ f32x4 mfma16(short8 a, short8 b, f32x4 c) {
  return __builtin_amdgcn_mfma_f32_16x16x32_bf16(a, b, c, 0, 0, 0);
}
static __device__ __forceinline__ uint pack_bf16(float a, float b) {
  __hip_bfloat162 h2 = __float22bfloat162_rn(make_float2(a, b));
  return *reinterpret_cast<uint*>(&h2);
}
// K-row permutation (R12-proven): physical row p -> LDS slot, chosen so the
// S^T C-layout ownership coincides with the PV B-operand k-ownership,
// making the P^T fragment pure register renaming.
static __device__ __forceinline__ int slot_of(int p) {
  return ((((p >> 2) & 1) * 2 + (p >> 5)) << 4) | (((p >> 3) & 3) << 2) | (p & 3);
}
// R13-proven XOR chunk swizzle (measured: bank conflicts 3.1M -> 0): col is
// a 16B-aligned ushort offset; XOR the 16B-chunk index with (row&7).  Same
// involution on write and read; LDS stride exactly 128B (LDK=64).
static __device__ __forceinline__ int swz(int row, int col) {
  return col ^ ((row & 7) << 3);
}

// ---------------------------------------------------------------------------
// Kernel 1 (pgemm v4, UNCHANGED).
// ---------------------------------------------------------------------------
__global__ __launch_bounds__(256, 2) void pgemm_kernel(
    const float* __restrict__ x,  const float* __restrict__ Wq,
    const float* __restrict__ Wk, const float* __restrict__ Wv,
    ushort* __restrict__ Qh, ushort* __restrict__ Ql,
    ushort* __restrict__ Kh, ushort* __restrict__ Kl,
    ushort* __restrict__ Vt) {
  __shared__ float sx[16][SXP];               // 33 KB; reused as merge buf
  float* mb = &sx[0][0];

  const int tid = threadIdx.x;
  const int wv = tid >> 6, lane = tid & 63;
  const int ln = lane & 15, qd = lane >> 4;
  const int rb = blockIdx.x * 16;

  {
    const float4* xg = reinterpret_cast<const float4*>(x + (size_t)rb * DIN);
#pragma unroll
    for (int j = 0; j < 8; ++j) {
      const int idx = tid + 256 * j;
      const int row = idx >> 7;
      const int col = (idx & 127) * 4;
      *reinterpret_cast<float4*>(&sx[row][col]) = xg[idx];
    }
  }
  __syncthreads();

  f32x4 acc[3][4];
#pragma unroll
  for (int m = 0; m < 3; ++m)
#pragma unroll
    for (int nt = 0; nt < 4; ++nt)
#pragma unroll
      for (int i = 0; i < 4; ++i) acc[m][nt][i] = 0.f;

  const int kb = wv * 128;
  const int wbase = (kb + qd * 8) * 64 + ln;

  float wf[2][32];
#define LDW(kt_, m_, buf_)                                                     \
  do {                                                                         \
    const float* W_ = ((m_) == 0) ? Wq : (((m_) == 1) ? Wk : Wv);              \
    const int o_ = wbase + (kt_) * 32 * 64;                                    \
    _Pragma("unroll") for (int nt = 0; nt < 4; ++nt)                           \
      _Pragma("unroll") for (int j = 0; j < 8; ++j)                            \
        wf[buf_][nt * 8 + j] = W_[o_ + j * 64 + nt * 16];                      \
  } while (0)

  LDW(0, 0, 0);
#pragma unroll
  for (int kt = 0; kt < 4; ++kt) {
    const int k0 = kb + kt * 32;
    float xs[8];
    *reinterpret_cast<float4*>(xs) =
        *reinterpret_cast<const float4*>(&sx[ln][k0 + qd * 8]);
    *reinterpret_cast<float4*>(xs + 4) =
        *reinterpret_cast<const float4*>(&sx[ln][k0 + qd * 8 + 4]);
    ushort ah[8] __attribute__((aligned(16)));
    ushort al[8] __attribute__((aligned(16)));
#pragma unroll
    for (int j = 0; j < 8; ++j) {
      const ushort h = bf16_of(xs[j]);
      ah[j] = h;
      al[j] = bf16_of(xs[j] - f_of_bf16(h));
    }
    const short8 Ah = *reinterpret_cast<short8*>(ah);
    const short8 Al = *reinterpret_cast<short8*>(al);
#pragma unroll
    for (int m = 0; m < 3; ++m) {
      const int g = kt * 3 + m;               // compile-time (unrolled)
      const int buf = g & 1;
      if (g < 11) {
        const int gn = g + 1;
        LDW(gn / 3, gn % 3, buf ^ 1);         // prefetch next group's W fp32
      }
      const float scale = (m == 0) ? 0.125f * 1.44269504088896f : 1.0f;
#pragma unroll
      for (int nt = 0; nt < 4; ++nt) {
        ushort bh8[8] __attribute__((aligned(16)));
        ushort bl8[8] __attribute__((aligned(16)));
#pragma unroll
        for (int j = 0; j < 8; ++j) {
          const float v = wf[buf][nt * 8 + j] * scale;
          const ushort h = bf16_of(v);
          bh8[j] = h;
          bl8[j] = bf16_of(v - f_of_bf16(h));
        }
        const short8 bh = *reinterpret_cast<short8*>(bh8);
        const short8 bl = *reinterpret_cast<short8*>(bl8);
        acc[m][nt] = mfma16(Ah, bh, acc[m][nt]);
        acc[m][nt] = mfma16(Ah, bl, acc[m][nt]);
        acc[m][nt] = mfma16(Al, bh, acc[m][nt]);
      }
    }
  }
#undef LDW

  const int eidx = (qd * 4) * 64 + ln;
  __syncthreads();
  if (wv >= 2) {
    float* b = mb + (size_t)(wv - 2) * 3072;
#pragma unroll
    for (int m = 0; m < 3; ++m)
#pragma unroll
      for (int nt = 0; nt < 4; ++nt)
#pragma unroll
        for (int r = 0; r < 4; ++r)
          b[m * 1024 + eidx + r * 64 + nt * 16] = acc[m][nt][r];
  }
  __syncthreads();
  if (wv < 2) {
    const float* b = mb + (size_t)wv * 3072;
#pragma unroll
    for (int m = 0; m < 3; ++m)
#pragma unroll
      for (int nt = 0; nt < 4; ++nt)
#pragma unroll
        for (int r = 0; r < 4; ++r)
          acc[m][nt][r] += b[m * 1024 + eidx + r * 64 + nt * 16];
  }
  __syncthreads();
  if (wv == 1) {
#pragma unroll
    for (int m = 0; m < 3; ++m)
#pragma unroll
      for (int nt = 0; nt < 4; ++nt)
#pragma unroll
        for (int r = 0; r < 4; ++r)
          mb[m * 1024 + eidx + r * 64 + nt * 16] = acc[m][nt][r];
  }
  __syncthreads();
  if (wv == 0) {
#pragma unroll
    for (int m = 0; m < 3; ++m)
#pragma unroll
      for (int nt = 0; nt < 4; ++nt)
#pragma unroll
        for (int r = 0; r < 4; ++r)
          acc[m][nt][r] += mb[m * 1024 + eidx + r * 64 + nt * 16];

#pragma unroll
    for (int m = 0; m < 2; ++m) {
      ushort* H = (m == 0) ? Qh : Kh;
      ushort* L = (m == 0) ? Ql : Kl;
#pragma unroll
      for (int nt = 0; nt < 4; ++nt)
#pragma unroll
        for (int r = 0; r < 4; ++r) {
          const float v = acc[m][nt][r];
          const int row = rb + qd * 4 + r;
          const int col = nt * 16 + ln;
          const ushort h = bf16_of(v);
          H[(size_t)row * DH + col] = h;
          L[(size_t)row * DH + col] = bf16_of(v - f_of_bf16(h));
        }
    }
#pragma unroll
    for (int nt = 0; nt < 4; ++nt) {
      ushort vp[4] __attribute__((aligned(8)));
#pragma unroll
      for (int r = 0; r < 4; ++r) vp[r] = bf16_of(acc[2][nt][r]);
      *reinterpret_cast<us4*>(Vt + (size_t)(nt * 16 + ln) * SEQ + rb + qd * 4) =
          *reinterpret_cast<us4*>(vp);
    }
  }
}

// ---------------------------------------------------------------------------
// Kernel 2 (flash v8): R15 QK-AHEAD PIPELINE.  Triple-buffered LDS (72 KB,
// 2 blocks/CU — R13/R14 proved 2 vs 3 blocks is perf-neutral, so spend LDS
// on pipeline depth instead).  Each iter: QK(t+1) MFMAs issue FIRST, then
// softmax(t) VALU — independent, so the matrix pipe drains under the
// exp2/scale chain instead of serializing (R14 post-mortem: intra-wave
// phase serialization, not occupancy, is the bound).  One barrier per iter
// via 3-buffer rotation (cur,nxt,sto) <- (nxt,sto,cur).  T13 defer-max:
// skip alpha-rescale when tile max <= m_run + 8 (wave-uniform branch;
// P bounded by 2^8, fine in f32 accum).
// ---------------------------------------------------------------------------
__global__ __launch_bounds__(256, 2) void flash_kernel(
    const ushort* __restrict__ Qh, const ushort* __restrict__ Ql,
    const ushort* __restrict__ Kh, const ushort* __restrict__ Kl,
    const ushort* __restrict__ Vt,
    ushort* __restrict__ Opart, float* __restrict__ Mpart,
    float* __restrict__ Lpart) {
  __shared__ __attribute__((aligned(16))) ushort sKh[3][BK][LDK];  // 24 KB
  __shared__ __attribute__((aligned(16))) ushort sKl[3][BK][LDK];  // 24 KB
  __shared__ __attribute__((aligned(16))) ushort sVt[3][DH][LDK];  // 24 KB

  const int tid  = threadIdx.x;
  const int wv   = tid >> 6;
  const int lane = tid & 63;
  const int ln   = lane & 15;
  const int qd   = lane >> 4;
  const int bid  = blockIdx.x;
  const int sg   = bid & (SG - 1);
  const int qt   = bid >> 3;            // 0..63 (128-row Q tiles)
  const int qrow0  = qt * 128 + wv * 32;   // set s adds s*16
  const int k0base = sg * CHUNK;

  const int r0 = tid >> 3, g0 = (tid & 7) * 8;
  const int r1 = r0 + 32,  g1 = g0;
  const int sr0 = slot_of(r0), sr1 = slot_of(r1);   // permuted K slots

  const ushort one_u = (ln == 0) ? (ushort)0x3F80 : (ushort)0;
  short8 afr1;
#pragma unroll
  for (int j = 0; j < 8; ++j) afr1[j] = (short)one_u;

  short8 bqh[2][2], bql[2][2];
#pragma unroll
  for (int s = 0; s < 2; ++s)
#pragma unroll
    for (int kt = 0; kt < 2; ++kt) {
      bqh[s][kt] = *reinterpret_cast<const short8*>(
          Qh + (size_t)(qrow0 + s * 16 + ln) * DH + kt * 32 + qd * 8);
      bql[s][kt] = *reinterpret_cast<const short8*>(
          Ql + (size_t)(qrow0 + s * 16 + ln) * DH + kt * 32 + qd * 8);
    }

  f32x4 accO[2][4], accL[2];
  float m_run[2] = {-INFINITY, -INFINITY};
#pragma unroll
  for (int s = 0; s < 2; ++s) {
#pragma unroll
    for (int nt = 0; nt < 4; ++nt)
#pragma unroll
      for (int i = 0; i < 4; ++i) accO[s][nt][i] = 0.f;
#pragma unroll
    for (int i = 0; i < 4; ++i) accL[s][i] = 0.f;
  }
  const f32x4 z4 = {0.f, 0.f, 0.f, 0.f};   // persistent zero C-operand

  f32x4 accSA[2][4], accSB[2][4];          // 2-deep S pipeline

  uint4 pk0, pk1, pl0, pl1, pv0, pv1;
#define LOAD_TILES(k0_)                                                        \
  do {                                                                         \
    pk0 = *reinterpret_cast<const uint4*>(Kh + (size_t)((k0_) + r0) * DH + g0);\
    pk1 = *reinterpret_cast<const uint4*>(Kh + (size_t)((k0_) + r1) * DH + g1);\
    pl0 = *reinterpret_cast<const uint4*>(Kl + (size_t)((k0_) + r0) * DH + g0);\
    pl1 = *reinterpret_cast<const uint4*>(Kl + (size_t)((k0_) + r1) * DH + g1);\
    pv0 = *reinterpret_cast<const uint4*>(Vt + (size_t)r0 * SEQ + (k0_) + g0); \
    pv1 = *reinterpret_cast<const uint4*>(Vt + (size_t)r1 * SEQ + (k0_) + g1); \
  } while (0)
#define STORE_TILES(b_)                                                        \
  do {                                                                         \
    *reinterpret_cast<uint4*>(&sKh[b_][sr0][swz(sr0, g0)]) = pk0;              \
    *reinterpret_cast<uint4*>(&sKh[b_][sr1][swz(sr1, g1)]) = pk1;              \
    *reinterpret_cast<uint4*>(&sKl[b_][sr0][swz(sr0, g0)]) = pl0;              \
    *reinterpret_cast<uint4*>(&sKl[b_][sr1][swz(sr1, g1)]) = pl1;              \
    *reinterpret_cast<uint4*>(&sVt[b_][r0][swz(r0, g0)])   = pv0;              \
    *reinterpret_cast<uint4*>(&sVt[b_][r1][swz(r1, g1)])   = pv1;              \
  } while (0)

  // QK^T of one tile from buffer b_ into ACC (hi*hi + hi*lo + lo*hi).
#define QK_PHASE(ACC, b_)                                                      \
  do {                                                                         \
    _Pragma("unroll") for (int nt = 0; nt < 4; ++nt) {                         \
      const int kr = nt * 16 + ln;                                             \
      const short8 kh0 = *reinterpret_cast<const short8*>(                     \
          &sKh[b_][kr][swz(kr, qd * 8)]);                                      \
      const short8 kh1 = *reinterpret_cast<const short8*>(                     \
          &sKh[b_][kr][swz(kr, 32 + qd * 8)]);                                 \
      const short8 kl0 = *reinterpret_cast<const short8*>(                     \
          &sKl[b_][kr][swz(kr, qd * 8)]);                                      \
      const short8 kl1 = *reinterpret_cast<const short8*>(                     \
          &sKl[b_][kr][swz(kr, 32 + qd * 8)]);                                 \
      _Pragma("unroll") for (int s = 0; s < 2; ++s) {                          \
        ACC[s][nt] = mfma16(kh0, bqh[s][0], z4);                               \
        ACC[s][nt] = mfma16(kh1, bqh[s][1], ACC[s][nt]);                       \
        ACC[s][nt] = mfma16(kh0, bql[s][0], ACC[s][nt]);                       \
        ACC[s][nt] = mfma16(kh1, bql[s][1], ACC[s][nt]);                       \
        ACC[s][nt] = mfma16(kl0, bqh[s][0], ACC[s][nt]);                       \
        ACC[s][nt] = mfma16(kl1, bqh[s][1], ACC[s][nt]);                       \
      }                                                                        \
    }                                                                          \
  } while (0)

  // softmax(ACC) with defer-max + PV from buffer bc_.
#define SMPV_PHASE(ACC, bc_)                                                   \
  do {                                                                         \
    uint pkd[2][4][2];                                                         \
    _Pragma("unroll") for (int s = 0; s < 2; ++s) {                            \
      float tmax = fmaxf(fmaxf(ACC[s][0][0], ACC[s][0][1]), ACC[s][0][2]);     \
      tmax = fmaxf(fmaxf(tmax, ACC[s][0][3]), ACC[s][1][0]);                   \
      tmax = fmaxf(fmaxf(tmax, ACC[s][1][1]), ACC[s][1][2]);                   \
      tmax = fmaxf(fmaxf(tmax, ACC[s][1][3]), ACC[s][2][0]);                   \
      tmax = fmaxf(fmaxf(tmax, ACC[s][2][1]), ACC[s][2][2]);                   \
      tmax = fmaxf(fmaxf(tmax, ACC[s][2][3]), ACC[s][3][0]);                   \
      tmax = fmaxf(fmaxf(tmax, ACC[s][3][1]), ACC[s][3][2]);                   \
      tmax = fmaxf(tmax, ACC[s][3][3]);                                        \
      tmax = fmaxf(tmax, __shfl_xor(tmax, 16));                                \
      tmax = fmaxf(tmax, __shfl_xor(tmax, 32));                                \
      if (tmax > m_run[s] + 8.f) {      /* T13: rescale only on real growth */ \
        const float mnew  = fmaxf(m_run[s], tmax);                             \
        const float alpha = exp2f(m_run[s] - mnew);                            \
        m_run[s] = mnew;                                                       \
        _Pragma("unroll") for (int nt = 0; nt < 4; ++nt)                       \
          _Pragma("unroll") for (int i = 0; i < 4; ++i)                        \
            accO[s][nt][i] *= alpha;                                           \
        accL[s][0] *= alpha;                                                   \
      }                                                                        \
      const float mr = m_run[s];                                               \
      _Pragma("unroll") for (int nt = 0; nt < 4; ++nt) {                       \
        pkd[s][nt][0] = pack_bf16(exp2f(ACC[s][nt][0] - mr),                   \
                                  exp2f(ACC[s][nt][1] - mr));                  \
        pkd[s][nt][1] = pack_bf16(exp2f(ACC[s][nt][2] - mr),                   \
                                  exp2f(ACC[s][nt][3] - mr));                  \
      }                                                                        \
    }                                                                          \
    _Pragma("unroll") for (int kt2 = 0; kt2 < 2; ++kt2) {                      \
      short8 pfrag[2];                                                         \
      _Pragma("unroll") for (int s = 0; s < 2; ++s) {                          \
        uint4 du;                                                              \
        du.x = pkd[s][kt2][0];                                                 \
        du.y = pkd[s][kt2][1];                                                 \
        du.z = pkd[s][kt2 + 2][0];                                             \
        du.w = pkd[s][kt2 + 2][1];                                             \
        pfrag[s] = *reinterpret_cast<short8*>(&du);                            \
      }                                                                        \
      _Pragma("unroll") for (int nt2 = 0; nt2 < 4; ++nt2) {                    \
        const int vr = nt2 * 16 + ln;                                          \
        const short8 vA = *reinterpret_cast<const short8*>(                    \
            &sVt[bc_][vr][swz(vr, kt2 * 32 + qd * 8)]);                        \
        accO[0][nt2] = mfma16(vA, pfrag[0], accO[0][nt2]);                     \
        accO[1][nt2] = mfma16(vA, pfrag[1], accO[1][nt2]);                     \
      }                                                                        \
      accL[0] = mfma16(afr1, pfrag[0], accL[0]);                               \
      accL[1] = mfma16(afr1, pfrag[1], accL[1]);                               \
    }                                                                          \
  } while (0)

  // ----- prologue: tile0 -> buf0 (+bar), QK(0), tile1 -> buf1 (+bar) -----
  LOAD_TILES(k0base);
  STORE_TILES(0);
  LOAD_TILES(k0base + BK);
  __syncthreads();
  QK_PHASE(accSA, 0);
  STORE_TILES(1);
  LOAD_TILES(k0base + 2 * BK);
  __syncthreads();

  int bc = 0, bn = 1, bs = 2;   // cur / next / store buffer roles
#define BODY(ACC_CUR, ACC_NXT, t_)                                             \
  do {                                                                         \
    if ((t_) + 1 < NIT) QK_PHASE(ACC_NXT, bn);   /* fills matrix pipe */       \
    SMPV_PHASE(ACC_CUR, bc);                     /* VALU under MFMA drain */   \
    if ((t_) + 2 < NIT) STORE_TILES(bs);                                       \
    if ((t_) + 3 < NIT) LOAD_TILES(k0base + ((t_) + 3) * BK);                  \
    if ((t_) + 1 < NIT) __syncthreads();                                       \
    const int tb_ = bc; bc = bn; bn = bs; bs = tb_;                            \
  } while (0)

  for (int t = 0; t < NIT; t += 2) {
    BODY(accSA, accSB, t);
    BODY(accSB, accSA, t + 1);
  }
#undef BODY
#undef QK_PHASE
#undef SMPV_PHASE
#undef LOAD_TILES
#undef STORE_TILES

#pragma unroll
  for (int s = 0; s < 2; ++s) {
    const int qrow = qrow0 + s * 16 + ln;
    ushort* Ob = Opart + ((size_t)sg * SEQ + qrow) * DH;
#pragma unroll
    for (int nt = 0; nt < 4; ++nt) {
      ushort op[4] __attribute__((aligned(8)));
#pragma unroll
      for (int r = 0; r < 4; ++r) op[r] = bf16_of(accO[s][nt][r]);
      *reinterpret_cast<us4*>(Ob + nt * 16 + qd * 4) =
          *reinterpret_cast<us4*>(op);
    }
    if (qd == 0) {
      Mpart[(size_t)sg * SEQ + qrow] = m_run[s];
      Lpart[(size_t)sg * SEQ + qrow] = accL[s][0];
    }
  }
}

// ---------------------------------------------------------------------------
// Kernel 3: merge of the SG=8 seq-split partials (exp2 domain), vec x4.
// ---------------------------------------------------------------------------
__global__ __launch_bounds__(256) void merge_kernel(
    const ushort* __restrict__ Opart, const float* __restrict__ Mpart,
    const float* __restrict__ Lpart, float* __restrict__ out) {
  const int idx = blockIdx.x * 256 + threadIdx.x;   // 0 .. SEQ*16
  const int row = idx >> 4;
  const int c4  = (idx & 15) * 4;

  float m[SG];
  float M = -INFINITY;
#pragma unroll
  for (int i = 0; i < SG; ++i) {
    m[i] = Mpart[(size_t)i * SEQ + row];
    M = fmaxf(M, m[i]);
  }
  float L = 0.f;
  float a0 = 0.f, a1 = 0.f, a2 = 0.f, a3 = 0.f;
#pragma unroll
  for (int i = 0; i < SG; ++i) {
    const float w = exp2f(m[i] - M);
    L += w * Lpart[(size_t)i * SEQ + row];
    const us4 o = *reinterpret_cast<const us4*>(
        Opart + ((size_t)i * SEQ + row) * DH + c4);
    a0 += w * f_of_bf16(o[0]);
    a1 += w * f_of_bf16(o[1]);
    a2 += w * f_of_bf16(o[2]);
    a3 += w * f_of_bf16(o[3]);
  }
  const float rL = 1.0f / L;
  float4 res = make_float4(a0 * rL, a1 * rL, a2 * rL, a3 * rL);
  *reinterpret_cast<float4*>(out + (size_t)row * DH + c4) = res;
}

// ---------------------------------------------------------------------------
extern "C" void kernel_launch(void* const* d_in, const int* in_sizes, int n_in,
                              void* d_out, int out_size, void* d_ws, size_t ws_size,
                              hipStream_t stream) {
  const float* x  = (const float*)d_in[0];
  const float* Wq = (const float*)d_in[1];
  const float* Wk = (const float*)d_in[2];
  const float* Wv = (const float*)d_in[3];
  float* out = (float*)d_out;

  // workspace layout — 14,155,776 B (SG=8 partials, as R12).
  const size_t S64 = (size_t)SEQ * DH;        // 524288
  ushort* Qh = (ushort*)d_ws;
  ushort* Ql = Qh + S64;
  ushort* Kh = Ql + S64;
  ushort* Kl = Kh + S64;
  ushort* Vt = Kl + S64;
  ushort* Op = Vt + S64;                      // [SG][SEQ][DH] bf16
  float*  Mp = (float*)(Op + (size_t)SG * S64);
  float*  Lp = Mp + (size_t)SG * SEQ;

  pgemm_kernel<<<SEQ / 16, 256, 0, stream>>>(x, Wq, Wk, Wv, Qh, Ql, Kh, Kl, Vt);
  flash_kernel<<<(SEQ / 128) * SG, 256, 0, stream>>>(Qh, Ql, Kh, Kl, Vt, Op, Mp, Lp);
  merge_kernel<<<(SEQ * 16) / 256, 256, 0, stream>>>(Op, Mp, Lp, out);
}